// Round 8
// baseline (829.695 us; speedup 1.0000x reference)
//
#include <hip/hip_runtime.h>
#include <hip/hip_bf16.h>
#include <hip/hip_fp16.h>
#include <math.h>

#define HD    128
#define EIN   325
#define PST   136      // pqr/x1/ef tile row stride (f16)
#define NST   264      // node A-tile row stride (f16)
#define XST   136      // x1 tile row stride
#define IST   408      // init A-tile row stride (400+8)

typedef _Float16 half8 __attribute__((ext_vector_type(8)));
typedef _Float16 half4v __attribute__((ext_vector_type(4)));
typedef float    floatx16 __attribute__((ext_vector_type(16)));

__device__ __forceinline__ float silu_f(float x) {
    return x / (1.0f + __expf(-x));
}

// ---- fused weight prep ----
__device__ __forceinline__ void wprep_one(const float* __restrict__ src, _Float16* __restrict__ dst,
                                          int idx, int Ktot, int krow0, int Kact, int Nn, int Kpad) {
    int per = Nn * Kpad;
    int m = idx / per, r = idx - m * per;
    int n = r / Kpad, k = r - n * Kpad;
    float v = (k < Kact) ? src[(size_t)m * Ktot * Nn + (size_t)(krow0 + k) * Nn + n] : 0.f;
    dst[idx] = (_Float16)v;
}

#define PREP_TOT 444416
__global__ void k_prep_all(const float* __restrict__ ew1, const float* __restrict__ ew2,
                           const float* __restrict__ nw1, const float* __restrict__ nw2,
                           const float* __restrict__ cw1, const float* __restrict__ lat_w,
                           _Float16* __restrict__ base) {
    int idx = blockIdx.x * 256 + threadIdx.x;
    if (idx >= PREP_TOT) return;
    if (idx < 65536)        wprep_one(ew1, base,          idx,          EIN, 0,   128, HD, HD);
    else if (idx < 131072)  wprep_one(ew1, base + 65536,  idx - 65536,  EIN, 128, 128, HD, HD);
    else if (idx < 163840)  wprep_one(ew1, base + 131072, idx - 131072, EIN, 265, 60,  HD, 64);
    else if (idx < 229376)  wprep_one(ew2, base + 163840, idx - 163840, HD,  0,   128, HD, HD);
    else if (idx < 327680)  wprep_one(nw1, base + 229376, idx - 229376, 256, 0,   256, HD, 256);
    else if (idx < 376832)  wprep_one(nw2, base + 327680, idx - 327680, HD,  0,   128, HD, HD);
    else if (idx < 393216)  wprep_one(cw1, base + 376832, idx - 376832, HD,  0,   128, HD, HD);
    else                    wprep_one(lat_w, base + 393216, idx - 393216, 384, 0, 384, HD, 400);
}

// ---- tiny kernels ----
__global__ void k_hist(const int* __restrict__ ei1, int* __restrict__ cnt, int E) {
    int idx = blockIdx.x * 256 + threadIdx.x;
    if (idx < E) atomicAdd(&cnt[ei1[idx]], 1);
}

__global__ __launch_bounds__(1024) void k_scan(const int* __restrict__ cnt,
                                               int* __restrict__ head,
                                               float* __restrict__ deginv, int N) {
    __shared__ int part[1024];
    int tid = threadIdx.x;
    int chunk = (N + 1023) >> 10;
    int start = tid * chunk, stop = min(start + chunk, N);
    int s = 0;
    for (int i = start; i < stop; ++i) {
        int cv = cnt[i];
        s += cv;
        deginv[i] = 1.0f / fmaxf((float)cv, 1.0f);
    }
    part[tid] = s;
    __syncthreads();
    for (int off = 1; off < 1024; off <<= 1) {
        int v = (tid >= off) ? part[tid - off] : 0;
        __syncthreads();
        part[tid] += v;
        __syncthreads();
    }
    int run = (tid > 0) ? part[tid - 1] : 0;
    for (int i = start; i < stop; ++i) { head[i] = run; run += cnt[i]; }
}

__global__ void k_scatter_es(const int* __restrict__ ei, const int* __restrict__ n2g,
                             const float* __restrict__ fc, int* __restrict__ head,
                             int* __restrict__ eaS, int* __restrict__ ebS,
                             int* __restrict__ egS, float* __restrict__ fdS, int E) {
    int e = blockIdx.x * 256 + threadIdx.x;
    if (e >= E) return;
    int a = ei[e], b = ei[E + e];
    int pos = atomicAdd(&head[b], 1);
    eaS[pos] = a; ebS[pos] = b; egS[pos] = n2g[a];
    #pragma unroll
    for (int d = 0; d < 3; ++d) {
        float sh = fc[b * 3 + d] - fc[a * 3 + d];
        fdS[pos * 3 + d] = sh - floorf(sh + 0.5f + 1e-4f);
    }
}

__global__ void k_rlat(const float* __restrict__ lat, const float* __restrict__ ew1,
                       const float* __restrict__ eb1, _Float16* __restrict__ R16, int G) {
    int idx = blockIdx.x * 256 + threadIdx.x;
    if (idx >= 4 * G * HD) return;
    int l = idx / (G * HD), r = idx - l * (G * HD), g = r >> 7, c = r & 127;
    const float* L = lat + g * 9;
    float lp[9];
    #pragma unroll
    for (int i = 0; i < 3; ++i)
        #pragma unroll
        for (int k = 0; k < 3; ++k)
            lp[i * 3 + k] = L[i*3+0]*L[k*3+0] + L[i*3+1]*L[k*3+1] + L[i*3+2]*L[k*3+2];
    const float* W = ew1 + (size_t)l * EIN * HD + 256 * HD;
    float s = eb1[l * HD + c];
    #pragma unroll
    for (int j = 0; j < 9; ++j) s = fmaf(lp[j], W[j * HD + c], s);
    R16[idx] = (_Float16)s;
}

__global__ void k_fin(const float* __restrict__ outsum, const float* __restrict__ deginv,
                      float* __restrict__ out, int N) {
    int idx = blockIdx.x * 256 + threadIdx.x;
    if (idx < N * 3) out[idx] = outsum[idx] * deginv[idx / 3];
}

// ---- node init + first P/Q, 64-node tiles (R4 version) ----
__global__ __launch_bounds__(256) void k_init_pq(
    const int* __restrict__ at, const float* __restrict__ t,
    const float* __restrict__ embed, const _Float16* __restrict__ latwT,
    const float* __restrict__ lat_b, float* __restrict__ h,
    _Float16* __restrict__ h16,
    const _Float16* __restrict__ WaT, const _Float16* __restrict__ WbT,
    _Float16* __restrict__ P16, _Float16* __restrict__ Q16, int N)
{
    __shared__ __align__(16) _Float16 xs[64 * IST];   // 51 KB
    __shared__ int   atL[64];
    __shared__ float tL[64];
    int tid = threadIdx.x;
    int n0  = blockIdx.x * 64;

    if (tid < 64) {
        int node = n0 + tid;
        atL[tid] = (node < N) ? at[node] - 1 : 0;
        tL[tid]  = (node < N) ? t[node] : 0.f;
    }
    __syncthreads();

    for (int c = tid; c < 64 * 32; c += 256) {       // embed cols 0..127
        int row = c >> 5, p = c & 31;
        float4 v = {0, 0, 0, 0};
        if (n0 + row < N) v = *(const float4*)(embed + (size_t)atL[row] * HD + p * 4);
        _Float16* d = xs + row * IST + p * 4;
        d[0] = (_Float16)v.x; d[1] = (_Float16)v.y; d[2] = (_Float16)v.z; d[3] = (_Float16)v.w;
    }
    for (int c = tid; c < 64 * 272; c += 256) {      // sin/cos cols 128..383 + pad
        int row = c / 272, j = c - row * 272;
        float v = 0.f;
        if (j < 256 && n0 + row < N) {
            int k = j & 127;
            float fr = __expf(-(float)k * 0.07252236514f);
            float a = tL[row] * fr;
            v = (j < 128) ? __sinf(a) : __cosf(a);
        }
        xs[row * IST + 128 + j] = (_Float16)v;
    }
    __syncthreads();

    int lane = tid & 63, wv = tid >> 6;
    int l31 = lane & 31, lh = lane >> 5;
    int rm = (wv >> 1) * 32, cb = (wv & 1) * 64;
    int n0c = cb + l31, n1c = cb + 32 + l31;

    floatx16 acc0 = {}, acc1 = {};
    {
        const _Float16* ap  = xs + (size_t)(rm + l31) * IST + lh * 8;
        const _Float16* bp0 = latwT + (size_t)n0c * 400 + lh * 8;
        const _Float16* bp1 = latwT + (size_t)n1c * 400 + lh * 8;
        for (int ks = 0; ks < 25; ++ks) {
            half8 a = *(const half8*)(ap + ks * 16);
            acc0 = __builtin_amdgcn_mfma_f32_32x32x16_f16(a, *(const half8*)(bp0 + ks * 16), acc0, 0, 0, 0);
            acc1 = __builtin_amdgcn_mfma_f32_32x32x16_f16(a, *(const half8*)(bp1 + ks * 16), acc1, 0, 0, 0);
        }
    }
    __syncthreads();

    {
        float b0 = lat_b[n0c], b1v = lat_b[n1c];
        #pragma unroll
        for (int r = 0; r < 16; ++r) {
            int row = rm + (r & 3) + 8 * (r >> 2) + 4 * lh;
            int node = n0 + row;
            float v0 = acc0[r] + b0, v1 = acc1[r] + b1v;
            _Float16 h0 = (_Float16)v0, h1 = (_Float16)v1;
            if (node < N) {
                h[(size_t)node * HD + n0c] = v0;
                h[(size_t)node * HD + n1c] = v1;
                h16[(size_t)node * HD + n0c] = h0;
                h16[(size_t)node * HD + n1c] = h1;
            }
            xs[row * PST + n0c] = h0;
            xs[row * PST + n1c] = h1;
        }
    }
    __syncthreads();

    {
        const _Float16* BT  = (wv & 1) ? WbT : WaT;
        _Float16*       OUT = (wv & 1) ? Q16 : P16;
        floatx16 acc[4] = {};
        const _Float16* ap = xs + (size_t)(rm + l31) * PST + lh * 8;
        for (int ks = 0; ks < 8; ++ks) {
            half8 a = *(const half8*)(ap + ks * 16);
            #pragma unroll
            for (int i = 0; i < 4; ++i) {
                half8 b = *(const half8*)(BT + (size_t)(i * 32 + l31) * HD + ks * 16 + lh * 8);
                acc[i] = __builtin_amdgcn_mfma_f32_32x32x16_f16(a, b, acc[i], 0, 0, 0);
            }
        }
        #pragma unroll
        for (int r = 0; r < 16; ++r) {
            int row = rm + (r & 3) + 8 * (r >> 2) + 4 * lh;
            int node = n0 + row;
            if (node < N) {
                #pragma unroll
                for (int i = 0; i < 4; ++i)
                    OUT[(size_t)node * HD + i * 32 + l31] = (_Float16)acc[i][r];
            }
        }
    }
}

// ---- edge kernel (R7 version: branch-resolved Chebyshev, b64 scatter) ----
#define PUTX(kk, val, LH) { if ((((kk) >> 3) & 1) == (LH)) afrag[(kk) >> 4][(kk) & 7] = (_Float16)(val); }
#define CHEB_FILL(LH)                                                         \
    _Pragma("unroll")                                                         \
    for (int d = 0; d < 3; ++d) {                                             \
        float ang = 6.283185307179586f * fdv[d];                              \
        float s1 = __sinf(ang), c1 = __cosf(ang);                             \
        float tc = 2.f * c1;                                                  \
        PUTX(30 + 10 * d + 0, 1.0f, LH);                                      \
        PUTX(10 * d + 1, s1, LH);                                             \
        PUTX(30 + 10 * d + 1, c1, LH);                                        \
        float sm2 = 0.f, sm1 = s1, cm2 = 1.f, cm1 = c1;                       \
        _Pragma("unroll")                                                     \
        for (int wq = 2; wq < 10; ++wq) {                                     \
            float sn = tc * sm1 - sm2;                                        \
            float cn = tc * cm1 - cm2;                                        \
            PUTX(10 * d + wq, sn, LH);                                        \
            PUTX(30 + 10 * d + wq, cn, LH);                                   \
            sm2 = sm1; sm1 = sn; cm2 = cm1; cm1 = cn;                         \
        }                                                                     \
    }

template <bool LAST>
__global__ __launch_bounds__(256) void k_edge(
    const int* __restrict__ eaS, const int* __restrict__ ebS,
    const int* __restrict__ egS, const float* __restrict__ fdS,
    const _Float16* __restrict__ P16, const _Float16* __restrict__ Q16,
    const _Float16* __restrict__ R16, const _Float16* __restrict__ WdT,
    const _Float16* __restrict__ W2T, const float* __restrict__ b2,
    const _Float16* __restrict__ cw1T, const float* __restrict__ cb1,
    const float* __restrict__ cw2,
    float* __restrict__ aggsum, float* __restrict__ outsum, int E)
{
    __shared__ __align__(16) _Float16 xt[64 * PST];   // 17.4 KB: PQR -> x1 -> ef
    __shared__ int   eaL[64], ebL[64], egL[64];
    __shared__ float fdlL[64][3];
    __shared__ float gateL[64];

    int tid = threadIdx.x;
    int s0  = blockIdx.x * 64;

    if (tid < 64) {
        int s = s0 + tid;
        if (s < E) {
            eaL[tid] = eaS[s]; ebL[tid] = ebS[s]; egL[tid] = egS[s];
            fdlL[tid][0] = fdS[s * 3];
            fdlL[tid][1] = fdS[s * 3 + 1];
            fdlL[tid][2] = fdS[s * 3 + 2];
        } else {
            eaL[tid] = 0; ebL[tid] = -1; egL[tid] = 0;
            fdlL[tid][0] = fdlL[tid][1] = fdlL[tid][2] = 0.f;
        }
        gateL[tid] = 0.f;
    }
    __syncthreads();

    for (int c = tid; c < 64 * 16; c += 256) {
        int row = c >> 4, p = c & 15;
        int b = ebL[row] < 0 ? 0 : ebL[row];
        half8 pv = *(const half8*)(P16 + (size_t)eaL[row] * HD + p * 8);
        half8 qv = *(const half8*)(Q16 + (size_t)b * HD + p * 8);
        half8 rv = *(const half8*)(R16 + (size_t)egL[row] * HD + p * 8);
        *(half8*)(xt + row * PST + p * 8) = pv + qv + rv;
    }

    int lane = tid & 63, wv = tid >> 6;
    int l31 = lane & 31, lh = lane >> 5;
    int rm = (wv >> 1) * 32, cb = (wv & 1) * 64;
    int n0c = cb + l31, n1c = cb + 32 + l31;
    int er = rm + l31;

    half8 afrag[4];
    #pragma unroll
    for (int i = 0; i < 4; ++i)
        #pragma unroll
        for (int j = 0; j < 8; ++j) afrag[i][j] = (_Float16)0.f;
    {
        float fdv[3] = {fdlL[er][0], fdlL[er][1], fdlL[er][2]};
        if (lh == 0) { CHEB_FILL(0) } else { CHEB_FILL(1) }
    }
    __syncthreads();

    floatx16 acc0 = {}, acc1 = {};
    {
        const _Float16* bp0 = WdT + (size_t)n0c * 64 + lh * 8;
        const _Float16* bp1 = WdT + (size_t)n1c * 64 + lh * 8;
        #pragma unroll
        for (int ks = 0; ks < 4; ++ks) {
            acc0 = __builtin_amdgcn_mfma_f32_32x32x16_f16(afrag[ks], *(const half8*)(bp0 + ks * 16), acc0, 0, 0, 0);
            acc1 = __builtin_amdgcn_mfma_f32_32x32x16_f16(afrag[ks], *(const half8*)(bp1 + ks * 16), acc1, 0, 0, 0);
        }
    }
    #pragma unroll
    for (int r = 0; r < 16; ++r) {
        int row = rm + (r & 3) + 8 * (r >> 2) + 4 * lh;
        float v0 = acc0[r] + (float)xt[row * PST + n0c];
        float v1 = acc1[r] + (float)xt[row * PST + n1c];
        xt[row * PST + n0c] = (_Float16)silu_f(v0);
        xt[row * PST + n1c] = (_Float16)silu_f(v1);
    }
    __syncthreads();

    acc0 = {}; acc1 = {};
    {
        const _Float16* ap  = xt + (size_t)er * PST + lh * 8;
        const _Float16* bp0 = W2T + (size_t)n0c * HD + lh * 8;
        const _Float16* bp1 = W2T + (size_t)n1c * HD + lh * 8;
        for (int ks = 0; ks < 8; ++ks) {
            half8 a = *(const half8*)(ap + ks * 16);
            acc0 = __builtin_amdgcn_mfma_f32_32x32x16_f16(a, *(const half8*)(bp0 + ks * 16), acc0, 0, 0, 0);
            acc1 = __builtin_amdgcn_mfma_f32_32x32x16_f16(a, *(const half8*)(bp1 + ks * 16), acc1, 0, 0, 0);
        }
    }
    __syncthreads();

    {
        float b20 = b2[n0c], b21 = b2[n1c];
        #pragma unroll
        for (int r = 0; r < 16; ++r) {
            int row = rm + (r & 3) + 8 * (r >> 2) + 4 * lh;
            xt[row * PST + n0c] = (_Float16)silu_f(acc0[r] + b20);
            xt[row * PST + n1c] = (_Float16)silu_f(acc1[r] + b21);
        }
    }
    __syncthreads();

    if (!LAST) {
        int cg  = (tid & 31) * 4;
        int rg0 = (tid >> 5) * 8;
        float sa[4] = {0.f, 0.f, 0.f, 0.f};
        int cur = -1;
        for (int r = rg0; r < rg0 + 8; ++r) {
            int d = ebL[r];
            half4v v = *(const half4v*)(xt + r * PST + cg);
            if (d != cur) {
                if (cur >= 0) {
                    #pragma unroll
                    for (int j = 0; j < 4; ++j)
                        atomicAdd(&aggsum[(size_t)cur * HD + cg + j], sa[j]);
                }
                cur = d;
                #pragma unroll
                for (int j = 0; j < 4; ++j) sa[j] = (float)v[j];
            } else {
                #pragma unroll
                for (int j = 0; j < 4; ++j) sa[j] += (float)v[j];
            }
        }
        if (cur >= 0) {
            #pragma unroll
            for (int j = 0; j < 4; ++j)
                atomicAdd(&aggsum[(size_t)cur * HD + cg + j], sa[j]);
        }
    } else {
        acc0 = {}; acc1 = {};
        {
            const _Float16* ap  = xt + (size_t)er * PST + lh * 8;
            const _Float16* bp0 = cw1T + (size_t)n0c * HD + lh * 8;
            const _Float16* bp1 = cw1T + (size_t)n1c * HD + lh * 8;
            for (int ks = 0; ks < 8; ++ks) {
                half8 a = *(const half8*)(ap + ks * 16);
                acc0 = __builtin_amdgcn_mfma_f32_32x32x16_f16(a, *(const half8*)(bp0 + ks * 16), acc0, 0, 0, 0);
                acc1 = __builtin_amdgcn_mfma_f32_32x32x16_f16(a, *(const half8*)(bp1 + ks * 16), acc1, 0, 0, 0);
            }
        }
        float cb0 = cb1[n0c], cb1v = cb1[n1c];
        float w0 = cw2[n0c],  w1 = cw2[n1c];
        #pragma unroll
        for (int r = 0; r < 16; ++r) {
            float p = silu_f(acc0[r] + cb0) * w0 + silu_f(acc1[r] + cb1v) * w1;
            p += __shfl_xor(p, 16);
            p += __shfl_xor(p, 8);
            p += __shfl_xor(p, 4);
            p += __shfl_xor(p, 2);
            p += __shfl_xor(p, 1);
            if (l31 == 0) {
                int row = rm + (r & 3) + 8 * (r >> 2) + 4 * lh;
                atomicAdd(&gateL[row], p);
            }
        }
        __syncthreads();
        if (tid < 64) {
            int r = tid, d = ebL[r];
            if (d >= 0 && (r == 0 || ebL[r - 1] != d)) {
                float sx = 0.f, sy = 0.f, sz = 0.f;
                for (int q = r; q < 64 && ebL[q] == d; ++q) {
                    float g = gateL[q];
                    sx += fdlL[q][0] * g; sy += fdlL[q][1] * g; sz += fdlL[q][2] * g;
                }
                atomicAdd(&outsum[d * 3 + 0], sx);
                atomicAdd(&outsum[d * 3 + 1], sy);
                atomicAdd(&outsum[d * 3 + 2], sz);
            }
        }
    }
}

// ---- node update + next-layer P/Q, 64-node tiles (R4 version) ----
__global__ __launch_bounds__(256) void k_node_pq(
    float* __restrict__ h, _Float16* __restrict__ h16,
    float* __restrict__ aggsum, const float* __restrict__ deginv,
    const _Float16* __restrict__ W1T, const float* __restrict__ b1,
    const _Float16* __restrict__ W2T, const float* __restrict__ b2,
    const _Float16* __restrict__ WaT, const _Float16* __restrict__ WbT,
    _Float16* __restrict__ P16, _Float16* __restrict__ Q16, int N)
{
    __shared__ __align__(16) _Float16 xs[64 * NST];   // 33.8 KB
    _Float16* x1s = xs;

    int tid = threadIdx.x;
    int n0  = blockIdx.x * 64;

    for (int c = tid; c < 64 * 16; c += 256) {
        int row = c >> 4, p = c & 15;
        int node = n0 + row;
        uint4 v = {0, 0, 0, 0};
        if (node < N) v = *(const uint4*)(h16 + (size_t)node * HD + p * 8);
        *(uint4*)(xs + row * NST + p * 8) = v;
    }
    for (int c = tid; c < 64 * HD; c += 256) {
        int row = c >> 7, cc = c & 127;
        int node = n0 + row;
        float v = 0.f;
        if (node < N) {
            size_t gi = (size_t)node * HD + cc;
            v = aggsum[gi] * deginv[node];
            aggsum[gi] = 0.f;
        }
        xs[row * NST + HD + cc] = (_Float16)v;
    }
    __syncthreads();

    int lane = tid & 63, wv = tid >> 6;
    int l31 = lane & 31, lh = lane >> 5;
    int rm = (wv >> 1) * 32, cbase = (wv & 1) * 64;
    int n0c = cbase + l31, n1c = cbase + 32 + l31;

    floatx16 acc0 = {}, acc1 = {};
    {
        const _Float16* ap  = xs  + (size_t)(rm + l31) * NST + lh * 8;
        const _Float16* bp0 = W1T + (size_t)n0c * 256 + lh * 8;
        const _Float16* bp1 = W1T + (size_t)n1c * 256 + lh * 8;
        for (int ks = 0; ks < 16; ++ks) {
            half8 a = *(const half8*)(ap + ks * 16);
            acc0 = __builtin_amdgcn_mfma_f32_32x32x16_f16(a, *(const half8*)(bp0 + ks * 16), acc0, 0, 0, 0);
            acc1 = __builtin_amdgcn_mfma_f32_32x32x16_f16(a, *(const half8*)(bp1 + ks * 16), acc1, 0, 0, 0);
        }
    }
    __syncthreads();
    {
        float b10 = b1[n0c], b11 = b1[n1c];
        #pragma unroll
        for (int r = 0; r < 16; ++r) {
            int row = rm + (r & 3) + 8 * (r >> 2) + 4 * lh;
            x1s[row * XST + n0c] = (_Float16)silu_f(acc0[r] + b10);
            x1s[row * XST + n1c] = (_Float16)silu_f(acc1[r] + b11);
        }
    }
    __syncthreads();

    acc0 = {}; acc1 = {};
    {
        const _Float16* ap  = x1s + (size_t)(rm + l31) * XST + lh * 8;
        const _Float16* bp0 = W2T + (size_t)n0c * HD + lh * 8;
        const _Float16* bp1 = W2T + (size_t)n1c * HD + lh * 8;
        for (int ks = 0; ks < 8; ++ks) {
            half8 a = *(const half8*)(ap + ks * 16);
            acc0 = __builtin_amdgcn_mfma_f32_32x32x16_f16(a, *(const half8*)(bp0 + ks * 16), acc0, 0, 0, 0);
            acc1 = __builtin_amdgcn_mfma_f32_32x32x16_f16(a, *(const half8*)(bp1 + ks * 16), acc1, 0, 0, 0);
        }
    }
    __syncthreads();

    {
        float b20 = b2[n0c], b21 = b2[n1c];
        #pragma unroll
        for (int r = 0; r < 16; ++r) {
            int row = rm + (r & 3) + 8 * (r >> 2) + 4 * lh;
            int node = n0 + row;
            float v0 = silu_f(acc0[r] + b20);
            float v1 = silu_f(acc1[r] + b21);
            _Float16 h0 = (_Float16)0.f, h1 = (_Float16)0.f;
            if (node < N) {
                size_t g0 = (size_t)node * HD + n0c;
                size_t g1 = (size_t)node * HD + n1c;
                v0 += h[g0]; v1 += h[g1];
                h[g0] = v0; h[g1] = v1;
                h0 = (_Float16)v0; h1 = (_Float16)v1;
                h16[g0] = h0; h16[g1] = h1;
            }
            xs[row * PST + n0c] = h0;
            xs[row * PST + n1c] = h1;
        }
    }
    __syncthreads();

    {
        const _Float16* BT  = (wv & 1) ? WbT : WaT;
        _Float16*       OUT = (wv & 1) ? Q16 : P16;
        floatx16 acc[4] = {};
        const _Float16* ap = xs + (size_t)(rm + l31) * PST + lh * 8;
        for (int ks = 0; ks < 8; ++ks) {
            half8 a = *(const half8*)(ap + ks * 16);
            #pragma unroll
            for (int i = 0; i < 4; ++i) {
                half8 b = *(const half8*)(BT + (size_t)(i * 32 + l31) * HD + ks * 16 + lh * 8);
                acc[i] = __builtin_amdgcn_mfma_f32_32x32x16_f16(a, b, acc[i], 0, 0, 0);
            }
        }
        #pragma unroll
        for (int r = 0; r < 16; ++r) {
            int row = rm + (r & 3) + 8 * (r >> 2) + 4 * lh;
            int node = n0 + row;
            if (node < N) {
                #pragma unroll
                for (int i = 0; i < 4; ++i)
                    OUT[(size_t)node * HD + i * 32 + l31] = (_Float16)acc[i][r];
            }
        }
    }
}

// ---------------- launcher ----------------
extern "C" void kernel_launch(void* const* d_in, const int* in_sizes, int n_in,
                              void* d_out, int out_size, void* d_ws, size_t ws_size,
                              hipStream_t stream)
{
    const int*   at    = (const int*)  d_in[0];
    const float* t     = (const float*)d_in[1];
    const float* fc    = (const float*)d_in[2];
    const int*   ei    = (const int*)  d_in[3];
    const float* lat   = (const float*)d_in[4];
    const int*   n2g   = (const int*)  d_in[5];
    const float* embed = (const float*)d_in[6];
    const float* lat_w = (const float*)d_in[7];
    const float* lat_b = (const float*)d_in[8];
    const float* ew1   = (const float*)d_in[9];
    const float* eb1   = (const float*)d_in[10];
    const float* ew2   = (const float*)d_in[11];
    const float* eb2   = (const float*)d_in[12];
    const float* nw1   = (const float*)d_in[13];
    const float* nb1   = (const float*)d_in[14];
    const float* nw2   = (const float*)d_in[15];
    const float* nb2   = (const float*)d_in[16];
    const float* cw1   = (const float*)d_in[17];
    const float* cb1   = (const float*)d_in[18];
    const float* cw2   = (const float*)d_in[19];

    int N = in_sizes[0];
    int E = in_sizes[3] / 2;
    int G = in_sizes[4] / 9;

    // ---- workspace carve ----
    char* p = (char*)d_ws;
    float* h      = (float*)p;  p += (size_t)N * HD * 4;
    float* aggsum = (float*)p;  p += (size_t)N * HD * 4;   // zeroed below
    float* outsum = (float*)p;  p += (size_t)N * 3 * 4;    // zeroed below
    int*   cnt    = (int*)p;    p += (size_t)N * 4;        // zeroed below
    int*   head   = (int*)p;    p += (size_t)N * 4;
    float* deginv = (float*)p;  p += (size_t)N * 4;
    int*   eaS    = (int*)p;    p += (size_t)E * 4;
    int*   ebS    = (int*)p;    p += (size_t)E * 4;
    int*   egS    = (int*)p;    p += (size_t)E * 4;
    float* fdS    = (float*)p;  p += (size_t)E * 3 * 4;
    _Float16* h16  = (_Float16*)p; p += (size_t)N * HD * 2;
    _Float16* P16  = (_Float16*)p; p += (size_t)N * HD * 2;
    _Float16* Q16  = (_Float16*)p; p += (size_t)N * HD * 2;
    _Float16* wbase = (_Float16*)p;
    _Float16* w1aT  = wbase;            // 65536
    _Float16* w1bT  = wbase + 65536;    // 65536
    _Float16* wdT   = wbase + 131072;   // 32768
    _Float16* w2T   = wbase + 163840;   // 65536
    _Float16* nw1T  = wbase + 229376;   // 98304
    _Float16* nw2T  = wbase + 327680;   // 49152
    _Float16* cw1T  = wbase + 376832;   // 16384
    _Float16* latwT = wbase + 393216;   // 51200
    p += (size_t)PREP_TOT * 2;
    _Float16* R16   = (_Float16*)p; p += (size_t)4 * G * HD * 2;

    hipMemsetAsync(aggsum, 0, ((size_t)N * HD + (size_t)N * 3 + N) * 4, stream);

    k_prep_all<<<(PREP_TOT + 255) / 256, 256, 0, stream>>>(ew1, ew2, nw1, nw2, cw1, lat_w, wbase);
    k_hist      <<<(E + 255) / 256, 256, 0, stream>>>(ei + E, cnt, E);
    k_scan      <<<1, 1024, 0, stream>>>(cnt, head, deginv, N);
    k_scatter_es<<<(E + 255) / 256, 256, 0, stream>>>(ei, n2g, fc, head, eaS, ebS, egS, fdS, E);
    k_rlat      <<<(4 * G * HD + 255) / 256, 256, 0, stream>>>(lat, ew1, eb1, R16, G);
    k_init_pq   <<<(N + 63) / 64, 256, 0, stream>>>(at, t, embed, latwT, lat_b, h, h16,
                                                    w1aT, w1bT, P16, Q16, N);

    int eblocks = (E + 63) / 64;
    int nblocks = (N + 63) / 64;
    for (int l = 0; l < 3; ++l) {
        k_edge<false><<<eblocks, 256, 0, stream>>>(eaS, ebS, egS, fdS, P16, Q16,
            R16 + (size_t)l * G * HD, wdT + (size_t)l * HD * 64,
            w2T + (size_t)l * HD * HD, eb2 + l * HD,
            cw1T, cb1, cw2, aggsum, outsum, E);
        k_node_pq<<<nblocks, 256, 0, stream>>>(h, h16, aggsum, deginv,
            nw1T + (size_t)l * HD * 256, nb1 + l * HD,
            nw2T + (size_t)l * HD * HD,  nb2 + l * HD,
            w1aT + (size_t)(l + 1) * HD * HD, w1bT + (size_t)(l + 1) * HD * HD,
            P16, Q16, N);
    }
    k_edge<true><<<eblocks, 256, 0, stream>>>(eaS, ebS, egS, fdS, P16, Q16,
        R16 + (size_t)3 * G * HD, wdT + (size_t)3 * HD * 64,
        w2T + (size_t)3 * HD * HD, eb2 + 3 * HD,
        cw1T, cb1, cw2, aggsum, outsum, E);

    k_fin<<<(N * 3 + 255) / 256, 256, 0, stream>>>(outsum, deginv, (float*)d_out, N);
}

// Round 9
// 774.599 us; speedup vs baseline: 1.0711x; 1.0711x over previous
//
#include <hip/hip_runtime.h>
#include <hip/hip_bf16.h>
#include <hip/hip_fp16.h>
#include <math.h>

#define HD    128
#define EIN   325
#define PST   136      // pqr/x1/ef tile row stride (f16)
#define NST   264      // node A-tile row stride (f16)
#define XST   136      // x1 tile row stride
#define IST   408      // init A-tile row stride (400+8)

typedef _Float16 half8 __attribute__((ext_vector_type(8)));
typedef _Float16 half4v __attribute__((ext_vector_type(4)));
typedef float    floatx16 __attribute__((ext_vector_type(16)));

__device__ __forceinline__ float silu_f(float x) {
    return x / (1.0f + __expf(-x));
}

// ---- fused weight prep ----
__device__ __forceinline__ void wprep_one(const float* __restrict__ src, _Float16* __restrict__ dst,
                                          int idx, int Ktot, int krow0, int Kact, int Nn, int Kpad) {
    int per = Nn * Kpad;
    int m = idx / per, r = idx - m * per;
    int n = r / Kpad, k = r - n * Kpad;
    float v = (k < Kact) ? src[(size_t)m * Ktot * Nn + (size_t)(krow0 + k) * Nn + n] : 0.f;
    dst[idx] = (_Float16)v;
}

#define PREP_TOT 444416
__global__ void k_prep_all(const float* __restrict__ ew1, const float* __restrict__ ew2,
                           const float* __restrict__ nw1, const float* __restrict__ nw2,
                           const float* __restrict__ cw1, const float* __restrict__ lat_w,
                           _Float16* __restrict__ base) {
    int idx = blockIdx.x * 256 + threadIdx.x;
    if (idx >= PREP_TOT) return;
    if (idx < 65536)        wprep_one(ew1, base,          idx,          EIN, 0,   128, HD, HD);
    else if (idx < 131072)  wprep_one(ew1, base + 65536,  idx - 65536,  EIN, 128, 128, HD, HD);
    else if (idx < 163840)  wprep_one(ew1, base + 131072, idx - 131072, EIN, 265, 60,  HD, 64);
    else if (idx < 229376)  wprep_one(ew2, base + 163840, idx - 163840, HD,  0,   128, HD, HD);
    else if (idx < 327680)  wprep_one(nw1, base + 229376, idx - 229376, 256, 0,   256, HD, 256);
    else if (idx < 376832)  wprep_one(nw2, base + 327680, idx - 327680, HD,  0,   128, HD, HD);
    else if (idx < 393216)  wprep_one(cw1, base + 376832, idx - 376832, HD,  0,   128, HD, HD);
    else                    wprep_one(lat_w, base + 393216, idx - 393216, 384, 0, 384, HD, 400);
}

// ---- tiny kernels ----
__global__ void k_hist(const int* __restrict__ ei1, int* __restrict__ cnt, int E) {
    int idx = blockIdx.x * 256 + threadIdx.x;
    if (idx < E) atomicAdd(&cnt[ei1[idx]], 1);
}

__global__ __launch_bounds__(1024) void k_scan(const int* __restrict__ cnt,
                                               int* __restrict__ head,
                                               float* __restrict__ deginv, int N) {
    __shared__ int part[1024];
    int tid = threadIdx.x;
    int chunk = (N + 1023) >> 10;
    int start = tid * chunk, stop = min(start + chunk, N);
    int s = 0;
    for (int i = start; i < stop; ++i) {
        int cv = cnt[i];
        s += cv;
        deginv[i] = 1.0f / fmaxf((float)cv, 1.0f);
    }
    part[tid] = s;
    __syncthreads();
    for (int off = 1; off < 1024; off <<= 1) {
        int v = (tid >= off) ? part[tid - off] : 0;
        __syncthreads();
        part[tid] += v;
        __syncthreads();
    }
    int run = (tid > 0) ? part[tid - 1] : 0;
    for (int i = start; i < stop; ++i) { head[i] = run; run += cnt[i]; }
}

__global__ void k_scatter_es(const int* __restrict__ ei, const int* __restrict__ n2g,
                             const float* __restrict__ fc, int* __restrict__ head,
                             int* __restrict__ eaS, int* __restrict__ ebS,
                             int* __restrict__ egS, float* __restrict__ fdS, int E) {
    int e = blockIdx.x * 256 + threadIdx.x;
    if (e >= E) return;
    int a = ei[e], b = ei[E + e];
    int pos = atomicAdd(&head[b], 1);
    eaS[pos] = a; ebS[pos] = b; egS[pos] = n2g[a];
    #pragma unroll
    for (int d = 0; d < 3; ++d) {
        float sh = fc[b * 3 + d] - fc[a * 3 + d];
        fdS[pos * 3 + d] = sh - floorf(sh + 0.5f + 1e-4f);
    }
}

__global__ void k_rlat(const float* __restrict__ lat, const float* __restrict__ ew1,
                       const float* __restrict__ eb1, _Float16* __restrict__ R16, int G) {
    int idx = blockIdx.x * 256 + threadIdx.x;
    if (idx >= 4 * G * HD) return;
    int l = idx / (G * HD), r = idx - l * (G * HD), g = r >> 7, c = r & 127;
    const float* L = lat + g * 9;
    float lp[9];
    #pragma unroll
    for (int i = 0; i < 3; ++i)
        #pragma unroll
        for (int k = 0; k < 3; ++k)
            lp[i * 3 + k] = L[i*3+0]*L[k*3+0] + L[i*3+1]*L[k*3+1] + L[i*3+2]*L[k*3+2];
    const float* W = ew1 + (size_t)l * EIN * HD + 256 * HD;
    float s = eb1[l * HD + c];
    #pragma unroll
    for (int j = 0; j < 9; ++j) s = fmaf(lp[j], W[j * HD + c], s);
    R16[idx] = (_Float16)s;
}

__global__ void k_fin(const float* __restrict__ outsum, const float* __restrict__ deginv,
                      float* __restrict__ out, int N) {
    int idx = blockIdx.x * 256 + threadIdx.x;
    if (idx < N * 3) out[idx] = outsum[idx] * deginv[idx / 3];
}

// ---- node init + first P/Q, 64-node tiles ----
__global__ __launch_bounds__(256) void k_init_pq(
    const int* __restrict__ at, const float* __restrict__ t,
    const float* __restrict__ embed, const _Float16* __restrict__ latwT,
    const float* __restrict__ lat_b, float* __restrict__ h,
    _Float16* __restrict__ h16,
    const _Float16* __restrict__ WaT, const _Float16* __restrict__ WbT,
    _Float16* __restrict__ P16, _Float16* __restrict__ Q16, int N)
{
    __shared__ __align__(16) _Float16 xs[64 * IST];   // 51 KB
    __shared__ int   atL[64];
    __shared__ float tL[64];
    int tid = threadIdx.x;
    int n0  = blockIdx.x * 64;

    if (tid < 64) {
        int node = n0 + tid;
        atL[tid] = (node < N) ? at[node] - 1 : 0;
        tL[tid]  = (node < N) ? t[node] : 0.f;
    }
    __syncthreads();

    for (int c = tid; c < 64 * 32; c += 256) {       // embed cols 0..127
        int row = c >> 5, p = c & 31;
        float4 v = {0, 0, 0, 0};
        if (n0 + row < N) v = *(const float4*)(embed + (size_t)atL[row] * HD + p * 4);
        _Float16* d = xs + row * IST + p * 4;
        d[0] = (_Float16)v.x; d[1] = (_Float16)v.y; d[2] = (_Float16)v.z; d[3] = (_Float16)v.w;
    }
    for (int c = tid; c < 64 * 272; c += 256) {      // sin/cos cols 128..383 + pad
        int row = c / 272, j = c - row * 272;
        float v = 0.f;
        if (j < 256 && n0 + row < N) {
            int k = j & 127;
            float fr = __expf(-(float)k * 0.07252236514f);
            float a = tL[row] * fr;
            v = (j < 128) ? __sinf(a) : __cosf(a);
        }
        xs[row * IST + 128 + j] = (_Float16)v;
    }
    __syncthreads();

    int lane = tid & 63, wv = tid >> 6;
    int l31 = lane & 31, lh = lane >> 5;
    int rm = (wv >> 1) * 32, cb = (wv & 1) * 64;
    int n0c = cb + l31, n1c = cb + 32 + l31;

    floatx16 acc0 = {}, acc1 = {};
    {
        const _Float16* ap  = xs + (size_t)(rm + l31) * IST + lh * 8;
        const _Float16* bp0 = latwT + (size_t)n0c * 400 + lh * 8;
        const _Float16* bp1 = latwT + (size_t)n1c * 400 + lh * 8;
        for (int ks = 0; ks < 25; ++ks) {
            half8 a = *(const half8*)(ap + ks * 16);
            acc0 = __builtin_amdgcn_mfma_f32_32x32x16_f16(a, *(const half8*)(bp0 + ks * 16), acc0, 0, 0, 0);
            acc1 = __builtin_amdgcn_mfma_f32_32x32x16_f16(a, *(const half8*)(bp1 + ks * 16), acc1, 0, 0, 0);
        }
    }
    __syncthreads();

    {
        float b0 = lat_b[n0c], b1v = lat_b[n1c];
        #pragma unroll
        for (int r = 0; r < 16; ++r) {
            int row = rm + (r & 3) + 8 * (r >> 2) + 4 * lh;
            int node = n0 + row;
            float v0 = acc0[r] + b0, v1 = acc1[r] + b1v;
            _Float16 h0 = (_Float16)v0, h1 = (_Float16)v1;
            if (node < N) {
                h[(size_t)node * HD + n0c] = v0;
                h[(size_t)node * HD + n1c] = v1;
                h16[(size_t)node * HD + n0c] = h0;
                h16[(size_t)node * HD + n1c] = h1;
            }
            xs[row * PST + n0c] = h0;
            xs[row * PST + n1c] = h1;
        }
    }
    __syncthreads();

    {
        const _Float16* BT  = (wv & 1) ? WbT : WaT;
        _Float16*       OUT = (wv & 1) ? Q16 : P16;
        floatx16 acc[4] = {};
        const _Float16* ap = xs + (size_t)(rm + l31) * PST + lh * 8;
        for (int ks = 0; ks < 8; ++ks) {
            half8 a = *(const half8*)(ap + ks * 16);
            #pragma unroll
            for (int i = 0; i < 4; ++i) {
                half8 b = *(const half8*)(BT + (size_t)(i * 32 + l31) * HD + ks * 16 + lh * 8);
                acc[i] = __builtin_amdgcn_mfma_f32_32x32x16_f16(a, b, acc[i], 0, 0, 0);
            }
        }
        #pragma unroll
        for (int r = 0; r < 16; ++r) {
            int row = rm + (r & 3) + 8 * (r >> 2) + 4 * lh;
            int node = n0 + row;
            if (node < N) {
                #pragma unroll
                for (int i = 0; i < 4; ++i)
                    OUT[(size_t)node * HD + i * 32 + l31] = (_Float16)acc[i][r];
            }
        }
    }
}

// ---- edge kernel: branch-resolved Chebyshev; <false>: register-direct scatter ----
#define PUTX(kk, val, LH) { if ((((kk) >> 3) & 1) == (LH)) afrag[(kk) >> 4][(kk) & 7] = (_Float16)(val); }
#define CHEB_FILL(LH)                                                         \
    _Pragma("unroll")                                                         \
    for (int d = 0; d < 3; ++d) {                                             \
        float ang = 6.283185307179586f * fdv[d];                              \
        float s1 = __sinf(ang), c1 = __cosf(ang);                             \
        float tc = 2.f * c1;                                                  \
        PUTX(30 + 10 * d + 0, 1.0f, LH);                                      \
        PUTX(10 * d + 1, s1, LH);                                             \
        PUTX(30 + 10 * d + 1, c1, LH);                                        \
        float sm2 = 0.f, sm1 = s1, cm2 = 1.f, cm1 = c1;                       \
        _Pragma("unroll")                                                     \
        for (int wq = 2; wq < 10; ++wq) {                                     \
            float sn = tc * sm1 - sm2;                                        \
            float cn = tc * cm1 - cm2;                                        \
            PUTX(10 * d + wq, sn, LH);                                        \
            PUTX(30 + 10 * d + wq, cn, LH);                                   \
            sm2 = sm1; sm1 = sn; cm2 = cm1; cm1 = cn;                         \
        }                                                                     \
    }

template <bool LAST>
__global__ __launch_bounds__(256) void k_edge(
    const int* __restrict__ eaS, const int* __restrict__ ebS,
    const int* __restrict__ egS, const float* __restrict__ fdS,
    const _Float16* __restrict__ P16, const _Float16* __restrict__ Q16,
    const _Float16* __restrict__ R16, const _Float16* __restrict__ WdT,
    const _Float16* __restrict__ W2T, const float* __restrict__ b2,
    const _Float16* __restrict__ cw1T, const float* __restrict__ cb1,
    const float* __restrict__ cw2,
    float* __restrict__ aggsum, float* __restrict__ outsum, int E)
{
    __shared__ __align__(16) _Float16 xt[64 * PST];   // 17.4 KB: PQR -> x1 (-> ef if LAST)
    __shared__ int   eaL[64], ebL[64], egL[64];
    __shared__ float fdlL[64][3];
    __shared__ float gateL[64];

    int tid = threadIdx.x;
    int s0  = blockIdx.x * 64;

    if (tid < 64) {
        int s = s0 + tid;
        if (s < E) {
            eaL[tid] = eaS[s]; ebL[tid] = ebS[s]; egL[tid] = egS[s];
            fdlL[tid][0] = fdS[s * 3];
            fdlL[tid][1] = fdS[s * 3 + 1];
            fdlL[tid][2] = fdS[s * 3 + 2];
        } else {
            eaL[tid] = 0; ebL[tid] = -1; egL[tid] = 0;
            fdlL[tid][0] = fdlL[tid][1] = fdlL[tid][2] = 0.f;
        }
        gateL[tid] = 0.f;
    }
    __syncthreads();

    for (int c = tid; c < 64 * 16; c += 256) {
        int row = c >> 4, p = c & 15;
        int b = ebL[row] < 0 ? 0 : ebL[row];
        half8 pv = *(const half8*)(P16 + (size_t)eaL[row] * HD + p * 8);
        half8 qv = *(const half8*)(Q16 + (size_t)b * HD + p * 8);
        half8 rv = *(const half8*)(R16 + (size_t)egL[row] * HD + p * 8);
        *(half8*)(xt + row * PST + p * 8) = pv + qv + rv;
    }

    int lane = tid & 63, wv = tid >> 6;
    int l31 = lane & 31, lh = lane >> 5;
    int rm = (wv >> 1) * 32, cb = (wv & 1) * 64;
    int n0c = cb + l31, n1c = cb + 32 + l31;
    int er = rm + l31;

    half8 afrag[4];
    #pragma unroll
    for (int i = 0; i < 4; ++i)
        #pragma unroll
        for (int j = 0; j < 8; ++j) afrag[i][j] = (_Float16)0.f;
    {
        float fdv[3] = {fdlL[er][0], fdlL[er][1], fdlL[er][2]};
        if (lh == 0) { CHEB_FILL(0) } else { CHEB_FILL(1) }
    }
    __syncthreads();

    floatx16 acc0 = {}, acc1 = {};
    {
        const _Float16* bp0 = WdT + (size_t)n0c * 64 + lh * 8;
        const _Float16* bp1 = WdT + (size_t)n1c * 64 + lh * 8;
        #pragma unroll
        for (int ks = 0; ks < 4; ++ks) {
            acc0 = __builtin_amdgcn_mfma_f32_32x32x16_f16(afrag[ks], *(const half8*)(bp0 + ks * 16), acc0, 0, 0, 0);
            acc1 = __builtin_amdgcn_mfma_f32_32x32x16_f16(afrag[ks], *(const half8*)(bp1 + ks * 16), acc1, 0, 0, 0);
        }
    }
    #pragma unroll
    for (int r = 0; r < 16; ++r) {
        int row = rm + (r & 3) + 8 * (r >> 2) + 4 * lh;
        float v0 = acc0[r] + (float)xt[row * PST + n0c];
        float v1 = acc1[r] + (float)xt[row * PST + n1c];
        xt[row * PST + n0c] = (_Float16)silu_f(v0);
        xt[row * PST + n1c] = (_Float16)silu_f(v1);
    }
    __syncthreads();

    // ---- GEMM2: ef = silu(x1 @ W2 + b2), K=128 ----
    acc0 = {}; acc1 = {};
    {
        const _Float16* ap  = xt + (size_t)er * PST + lh * 8;
        const _Float16* bp0 = W2T + (size_t)n0c * HD + lh * 8;
        const _Float16* bp1 = W2T + (size_t)n1c * HD + lh * 8;
        for (int ks = 0; ks < 8; ++ks) {
            half8 a = *(const half8*)(ap + ks * 16);
            acc0 = __builtin_amdgcn_mfma_f32_32x32x16_f16(a, *(const half8*)(bp0 + ks * 16), acc0, 0, 0, 0);
            acc1 = __builtin_amdgcn_mfma_f32_32x32x16_f16(a, *(const half8*)(bp1 + ks * 16), acc1, 0, 0, 0);
        }
    }

    if (!LAST) {
        // register-direct run-reduced scatter: lane owns cols n0c/n1c, 4 groups of
        // 4 consecutive sorted edges each -> no ef LDS round trip, no barriers.
        float b20 = b2[n0c], b21 = b2[n1c];
        #pragma unroll
        for (int g = 0; g < 4; ++g) {
            int base = rm + 4 * lh + 8 * g;
            int cur = -1;
            float sx = 0.f, sy = 0.f;
            #pragma unroll
            for (int j = 0; j < 4; ++j) {
                int d = ebL[base + j];
                float v0 = silu_f(acc0[g * 4 + j] + b20);
                float v1 = silu_f(acc1[g * 4 + j] + b21);
                if (d != cur) {
                    if (cur >= 0) {
                        atomicAdd(&aggsum[(size_t)cur * HD + n0c], sx);
                        atomicAdd(&aggsum[(size_t)cur * HD + n1c], sy);
                    }
                    cur = d; sx = v0; sy = v1;
                } else { sx += v0; sy += v1; }
            }
            if (cur >= 0) {
                atomicAdd(&aggsum[(size_t)cur * HD + n0c], sx);
                atomicAdd(&aggsum[(size_t)cur * HD + n1c], sy);
            }
        }
    } else {
        __syncthreads();   // all waves done reading x1
        {
            float b20 = b2[n0c], b21 = b2[n1c];
            #pragma unroll
            for (int r = 0; r < 16; ++r) {
                int row = rm + (r & 3) + 8 * (r >> 2) + 4 * lh;
                xt[row * PST + n0c] = (_Float16)silu_f(acc0[r] + b20);
                xt[row * PST + n1c] = (_Float16)silu_f(acc1[r] + b21);
            }
        }
        __syncthreads();   // ef complete

        acc0 = {}; acc1 = {};
        {
            const _Float16* ap  = xt + (size_t)er * PST + lh * 8;
            const _Float16* bp0 = cw1T + (size_t)n0c * HD + lh * 8;
            const _Float16* bp1 = cw1T + (size_t)n1c * HD + lh * 8;
            for (int ks = 0; ks < 8; ++ks) {
                half8 a = *(const half8*)(ap + ks * 16);
                acc0 = __builtin_amdgcn_mfma_f32_32x32x16_f16(a, *(const half8*)(bp0 + ks * 16), acc0, 0, 0, 0);
                acc1 = __builtin_amdgcn_mfma_f32_32x32x16_f16(a, *(const half8*)(bp1 + ks * 16), acc1, 0, 0, 0);
            }
        }
        float cb0 = cb1[n0c], cb1v = cb1[n1c];
        float w0 = cw2[n0c],  w1 = cw2[n1c];
        #pragma unroll
        for (int r = 0; r < 16; ++r) {
            float p = silu_f(acc0[r] + cb0) * w0 + silu_f(acc1[r] + cb1v) * w1;
            p += __shfl_xor(p, 16);
            p += __shfl_xor(p, 8);
            p += __shfl_xor(p, 4);
            p += __shfl_xor(p, 2);
            p += __shfl_xor(p, 1);
            if (l31 == 0) {
                int row = rm + (r & 3) + 8 * (r >> 2) + 4 * lh;
                atomicAdd(&gateL[row], p);
            }
        }
        __syncthreads();
        if (tid < 64) {
            int r = tid, d = ebL[r];
            if (d >= 0 && (r == 0 || ebL[r - 1] != d)) {
                float sx = 0.f, sy = 0.f, sz = 0.f;
                for (int q = r; q < 64 && ebL[q] == d; ++q) {
                    float g = gateL[q];
                    sx += fdlL[q][0] * g; sy += fdlL[q][1] * g; sz += fdlL[q][2] * g;
                }
                atomicAdd(&outsum[d * 3 + 0], sx);
                atomicAdd(&outsum[d * 3 + 1], sy);
                atomicAdd(&outsum[d * 3 + 2], sz);
            }
        }
    }
}

// ---- node update + next-layer P/Q, 64-node tiles ----
__global__ __launch_bounds__(256) void k_node_pq(
    float* __restrict__ h, _Float16* __restrict__ h16,
    float* __restrict__ aggsum, const float* __restrict__ deginv,
    const _Float16* __restrict__ W1T, const float* __restrict__ b1,
    const _Float16* __restrict__ W2T, const float* __restrict__ b2,
    const _Float16* __restrict__ WaT, const _Float16* __restrict__ WbT,
    _Float16* __restrict__ P16, _Float16* __restrict__ Q16, int N)
{
    __shared__ __align__(16) _Float16 xs[64 * NST];   // 33.8 KB
    _Float16* x1s = xs;

    int tid = threadIdx.x;
    int n0  = blockIdx.x * 64;

    for (int c = tid; c < 64 * 16; c += 256) {
        int row = c >> 4, p = c & 15;
        int node = n0 + row;
        uint4 v = {0, 0, 0, 0};
        if (node < N) v = *(const uint4*)(h16 + (size_t)node * HD + p * 8);
        *(uint4*)(xs + row * NST + p * 8) = v;
    }
    for (int c = tid; c < 64 * HD; c += 256) {
        int row = c >> 7, cc = c & 127;
        int node = n0 + row;
        float v = 0.f;
        if (node < N) {
            size_t gi = (size_t)node * HD + cc;
            v = aggsum[gi] * deginv[node];
            aggsum[gi] = 0.f;
        }
        xs[row * NST + HD + cc] = (_Float16)v;
    }
    __syncthreads();

    int lane = tid & 63, wv = tid >> 6;
    int l31 = lane & 31, lh = lane >> 5;
    int rm = (wv >> 1) * 32, cbase = (wv & 1) * 64;
    int n0c = cbase + l31, n1c = cbase + 32 + l31;

    floatx16 acc0 = {}, acc1 = {};
    {
        const _Float16* ap  = xs  + (size_t)(rm + l31) * NST + lh * 8;
        const _Float16* bp0 = W1T + (size_t)n0c * 256 + lh * 8;
        const _Float16* bp1 = W1T + (size_t)n1c * 256 + lh * 8;
        for (int ks = 0; ks < 16; ++ks) {
            half8 a = *(const half8*)(ap + ks * 16);
            acc0 = __builtin_amdgcn_mfma_f32_32x32x16_f16(a, *(const half8*)(bp0 + ks * 16), acc0, 0, 0, 0);
            acc1 = __builtin_amdgcn_mfma_f32_32x32x16_f16(a, *(const half8*)(bp1 + ks * 16), acc1, 0, 0, 0);
        }
    }
    __syncthreads();
    {
        float b10 = b1[n0c], b11 = b1[n1c];
        #pragma unroll
        for (int r = 0; r < 16; ++r) {
            int row = rm + (r & 3) + 8 * (r >> 2) + 4 * lh;
            x1s[row * XST + n0c] = (_Float16)silu_f(acc0[r] + b10);
            x1s[row * XST + n1c] = (_Float16)silu_f(acc1[r] + b11);
        }
    }
    __syncthreads();

    acc0 = {}; acc1 = {};
    {
        const _Float16* ap  = x1s + (size_t)(rm + l31) * XST + lh * 8;
        const _Float16* bp0 = W2T + (size_t)n0c * HD + lh * 8;
        const _Float16* bp1 = W2T + (size_t)n1c * HD + lh * 8;
        for (int ks = 0; ks < 8; ++ks) {
            half8 a = *(const half8*)(ap + ks * 16);
            acc0 = __builtin_amdgcn_mfma_f32_32x32x16_f16(a, *(const half8*)(bp0 + ks * 16), acc0, 0, 0, 0);
            acc1 = __builtin_amdgcn_mfma_f32_32x32x16_f16(a, *(const half8*)(bp1 + ks * 16), acc1, 0, 0, 0);
        }
    }
    __syncthreads();

    {
        float b20 = b2[n0c], b21 = b2[n1c];
        #pragma unroll
        for (int r = 0; r < 16; ++r) {
            int row = rm + (r & 3) + 8 * (r >> 2) + 4 * lh;
            int node = n0 + row;
            float v0 = silu_f(acc0[r] + b20);
            float v1 = silu_f(acc1[r] + b21);
            _Float16 h0 = (_Float16)0.f, h1 = (_Float16)0.f;
            if (node < N) {
                size_t g0 = (size_t)node * HD + n0c;
                size_t g1 = (size_t)node * HD + n1c;
                v0 += h[g0]; v1 += h[g1];
                h[g0] = v0; h[g1] = v1;
                h0 = (_Float16)v0; h1 = (_Float16)v1;
                h16[g0] = h0; h16[g1] = h1;
            }
            xs[row * PST + n0c] = h0;
            xs[row * PST + n1c] = h1;
        }
    }
    __syncthreads();

    {
        const _Float16* BT  = (wv & 1) ? WbT : WaT;
        _Float16*       OUT = (wv & 1) ? Q16 : P16;
        floatx16 acc[4] = {};
        const _Float16* ap = xs + (size_t)(rm + l31) * PST + lh * 8;
        for (int ks = 0; ks < 8; ++ks) {
            half8 a = *(const half8*)(ap + ks * 16);
            #pragma unroll
            for (int i = 0; i < 4; ++i) {
                half8 b = *(const half8*)(BT + (size_t)(i * 32 + l31) * HD + ks * 16 + lh * 8);
                acc[i] = __builtin_amdgcn_mfma_f32_32x32x16_f16(a, b, acc[i], 0, 0, 0);
            }
        }
        #pragma unroll
        for (int r = 0; r < 16; ++r) {
            int row = rm + (r & 3) + 8 * (r >> 2) + 4 * lh;
            int node = n0 + row;
            if (node < N) {
                #pragma unroll
                for (int i = 0; i < 4; ++i)
                    OUT[(size_t)node * HD + i * 32 + l31] = (_Float16)acc[i][r];
            }
        }
    }
}

// ---------------- launcher ----------------
extern "C" void kernel_launch(void* const* d_in, const int* in_sizes, int n_in,
                              void* d_out, int out_size, void* d_ws, size_t ws_size,
                              hipStream_t stream)
{
    const int*   at    = (const int*)  d_in[0];
    const float* t     = (const float*)d_in[1];
    const float* fc    = (const float*)d_in[2];
    const int*   ei    = (const int*)  d_in[3];
    const float* lat   = (const float*)d_in[4];
    const int*   n2g   = (const int*)  d_in[5];
    const float* embed = (const float*)d_in[6];
    const float* lat_w = (const float*)d_in[7];
    const float* lat_b = (const float*)d_in[8];
    const float* ew1   = (const float*)d_in[9];
    const float* eb1   = (const float*)d_in[10];
    const float* ew2   = (const float*)d_in[11];
    const float* eb2   = (const float*)d_in[12];
    const float* nw1   = (const float*)d_in[13];
    const float* nb1   = (const float*)d_in[14];
    const float* nw2   = (const float*)d_in[15];
    const float* nb2   = (const float*)d_in[16];
    const float* cw1   = (const float*)d_in[17];
    const float* cb1   = (const float*)d_in[18];
    const float* cw2   = (const float*)d_in[19];

    int N = in_sizes[0];
    int E = in_sizes[3] / 2;
    int G = in_sizes[4] / 9;

    // ---- workspace carve ----
    char* p = (char*)d_ws;
    float* h      = (float*)p;  p += (size_t)N * HD * 4;
    float* aggsum = (float*)p;  p += (size_t)N * HD * 4;   // zeroed below
    float* outsum = (float*)p;  p += (size_t)N * 3 * 4;    // zeroed below
    int*   cnt    = (int*)p;    p += (size_t)N * 4;        // zeroed below
    int*   head   = (int*)p;    p += (size_t)N * 4;
    float* deginv = (float*)p;  p += (size_t)N * 4;
    int*   eaS    = (int*)p;    p += (size_t)E * 4;
    int*   ebS    = (int*)p;    p += (size_t)E * 4;
    int*   egS    = (int*)p;    p += (size_t)E * 4;
    float* fdS    = (float*)p;  p += (size_t)E * 3 * 4;
    _Float16* h16  = (_Float16*)p; p += (size_t)N * HD * 2;
    _Float16* P16  = (_Float16*)p; p += (size_t)N * HD * 2;
    _Float16* Q16  = (_Float16*)p; p += (size_t)N * HD * 2;
    _Float16* wbase = (_Float16*)p;
    _Float16* w1aT  = wbase;            // 65536
    _Float16* w1bT  = wbase + 65536;    // 65536
    _Float16* wdT   = wbase + 131072;   // 32768
    _Float16* w2T   = wbase + 163840;   // 65536
    _Float16* nw1T  = wbase + 229376;   // 98304
    _Float16* nw2T  = wbase + 327680;   // 49152
    _Float16* cw1T  = wbase + 376832;   // 16384
    _Float16* latwT = wbase + 393216;   // 51200
    p += (size_t)PREP_TOT * 2;
    _Float16* R16   = (_Float16*)p; p += (size_t)4 * G * HD * 2;

    hipMemsetAsync(aggsum, 0, ((size_t)N * HD + (size_t)N * 3 + N) * 4, stream);

    k_prep_all<<<(PREP_TOT + 255) / 256, 256, 0, stream>>>(ew1, ew2, nw1, nw2, cw1, lat_w, wbase);
    k_hist      <<<(E + 255) / 256, 256, 0, stream>>>(ei + E, cnt, E);
    k_scan      <<<1, 1024, 0, stream>>>(cnt, head, deginv, N);
    k_scatter_es<<<(E + 255) / 256, 256, 0, stream>>>(ei, n2g, fc, head, eaS, ebS, egS, fdS, E);
    k_rlat      <<<(4 * G * HD + 255) / 256, 256, 0, stream>>>(lat, ew1, eb1, R16, G);
    k_init_pq   <<<(N + 63) / 64, 256, 0, stream>>>(at, t, embed, latwT, lat_b, h, h16,
                                                    w1aT, w1bT, P16, Q16, N);

    int eblocks = (E + 63) / 64;
    int nblocks = (N + 63) / 64;
    for (int l = 0; l < 3; ++l) {
        k_edge<false><<<eblocks, 256, 0, stream>>>(eaS, ebS, egS, fdS, P16, Q16,
            R16 + (size_t)l * G * HD, wdT + (size_t)l * HD * 64,
            w2T + (size_t)l * HD * HD, eb2 + l * HD,
            cw1T, cb1, cw2, aggsum, outsum, E);
        k_node_pq<<<nblocks, 256, 0, stream>>>(h, h16, aggsum, deginv,
            nw1T + (size_t)l * HD * 256, nb1 + l * HD,
            nw2T + (size_t)l * HD * HD,  nb2 + l * HD,
            w1aT + (size_t)(l + 1) * HD * HD, w1bT + (size_t)(l + 1) * HD * HD,
            P16, Q16, N);
    }
    k_edge<true><<<eblocks, 256, 0, stream>>>(eaS, ebS, egS, fdS, P16, Q16,
        R16 + (size_t)3 * G * HD, wdT + (size_t)3 * HD * 64,
        w2T + (size_t)3 * HD * HD, eb2 + 3 * HD,
        cw1T, cb1, cw2, aggsum, outsum, E);

    k_fin<<<(N * 3 + 255) / 256, 256, 0, stream>>>(outsum, deginv, (float*)d_out, N);
}